// Round 15
// baseline (95.659 us; speedup 1.0000x reference)
//
#include <hip/hip_runtime.h>
#include <math.h>

// RESUS_NN_2327872274812: Q=8192, S=30, D=512.  FP32-exact, deterministic.
// r15 = r14 with query-multiplicity R=2: each thread owns TWO queries'
// 16-float d-slices (48 pinned regs, fewer than r11's proven 64). Each
// 4xb128 support read now feeds 2 queries -> support-read instr count
// HALVES (1920 -> 960 per CU). r14 showed the wall is LDS issue cycles on
// broadcast-heavy b128 (4 distinct addrs/instr ~24cyc); here reads have 8
// distinct addrs on 8 distinct bank-quads (seg stride 20 floats: quad =
// 5*dseg mod 8 is a permutation) -> conflict-free, more unique B/instr.
// thread = (qpair 0..7, dseg 0..31, shalf 0..1): queries {qpair, qpair+8},
// d-slice [16*dseg, +16), 3 support rows per pass (SCHUNK=6, NPASS=5).

#define QN 8192
#define SN 30
#define DN 512
#define BLK 512
#define QT 16            // queries per block
#define SCHUNK 6         // support rows per pass
#define NPASS 5
#define SROW 644         // floats per LDS support row (32 segs * 20 + 4)
#define PQS 17           // praw q-dim stride (floats)
#define SLSTR 545        // praw sl-dim stride (32*17 + 1 -> +sl bank skew)
#define PSTR 31          // final part row stride (float2)

__global__ __launch_bounds__(BLK, 2)
void resus_one(const float* __restrict__ query,      // [Q][D]
               const float* __restrict__ support,    // [S][D]
               const float* __restrict__ support_y,  // [S]
               const float* __restrict__ support_pr, // [S]
               const float* __restrict__ query_pr,   // [Q]
               const float* __restrict__ fc1_w,      // [D]
               const float* __restrict__ adj_scale,  // [30]
               const float* __restrict__ adj_bias,   // [30]
               const int*   __restrict__ num_samples,// [1]
               float* __restrict__ out)              // [2*Q]
{
    __shared__ float  sp[SCHUNK * SROW];      // 15,456 B
    __shared__ float  praw_sc[SCHUNK * SLSTR];// 13,080 B
    __shared__ float  praw_sq[SCHUNK * SLSTR];// 13,080 B
    __shared__ float2 part[QT * PSTR];        //  3,968 B   total 45,584 B

    const int tid   = threadIdx.x;
    const int qpair = tid & 7;                // 0..7
    const int dseg  = (tid >> 3) & 31;        // 16-float d-segment
    const int shalf = tid >> 8;               // 0/1: rows 0-2 or 3-5 of chunk
    const int qA    = blockIdx.x * QT + qpair;
    const int qB    = qA + 8;

    // ---- one-time: 2 query slices + w slice into named regs, PINNED ----
    const float* qpA = query + (size_t)qA * DN + dseg * 16;
    float4 a0 = *reinterpret_cast<const float4*>(qpA +  0);
    float4 a1 = *reinterpret_cast<const float4*>(qpA +  4);
    float4 a2 = *reinterpret_cast<const float4*>(qpA +  8);
    float4 a3 = *reinterpret_cast<const float4*>(qpA + 12);
    const float* qpB = query + (size_t)qB * DN + dseg * 16;
    float4 b0 = *reinterpret_cast<const float4*>(qpB +  0);
    float4 b1 = *reinterpret_cast<const float4*>(qpB +  4);
    float4 b2 = *reinterpret_cast<const float4*>(qpB +  8);
    float4 b3 = *reinterpret_cast<const float4*>(qpB + 12);
    const float* wp = fc1_w + dseg * 16;
    float4 w0 = *reinterpret_cast<const float4*>(wp +  0);
    float4 w1 = *reinterpret_cast<const float4*>(wp +  4);
    float4 w2 = *reinterpret_cast<const float4*>(wp +  8);
    float4 w3 = *reinterpret_cast<const float4*>(wp + 12);

#define PIN4(V) asm volatile("" : "+v"((V).x), "+v"((V).y), "+v"((V).z), "+v"((V).w))
    PIN4(a0); PIN4(a1); PIN4(a2); PIN4(a3);
    PIN4(b0); PIN4(b1); PIN4(b2); PIN4(b3);
    PIN4(w0); PIN4(w1); PIN4(w2); PIN4(w3);
#undef PIN4

#define ACC4(QV, WV, SV, SC, SQ) { float d_; \
    d_ = (QV).x - (SV).x; SC = fmaf((WV).x, fabsf(d_), SC); SQ = fmaf(d_, d_, SQ); \
    d_ = (QV).y - (SV).y; SC = fmaf((WV).y, fabsf(d_), SC); SQ = fmaf(d_, d_, SQ); \
    d_ = (QV).z - (SV).z; SC = fmaf((WV).z, fabsf(d_), SC); SQ = fmaf(d_, d_, SQ); \
    d_ = (QV).w - (SV).w; SC = fmaf((WV).w, fabsf(d_), SC); SQ = fmaf(d_, d_, SQ); }

    const int sbase = dseg * 20;              // seg stride 20 -> quad 5*dseg%8
    const int sl0   = shalf * (SCHUNK / 2);   // 0 or 3

    for (int pass = 0; pass < NPASS; ++pass) {
        __syncthreads();   // prev pass: sp reads + reduce complete

        // ---- stage 6 support rows (coalesced read -> segmented LDS) ----
        const float4* sg = reinterpret_cast<const float4*>(
            support + (size_t)pass * SCHUNK * DN);
        for (int i = tid; i < SCHUNK * 128; i += BLK) {
            const int row = i >> 7, c4 = i & 127;
            *reinterpret_cast<float4*>(
                sp + row * SROW + 20 * (c4 >> 2) + 4 * (c4 & 3)) = sg[i];
        }
        __syncthreads();

        // ---- hot loop: 3 rows/thread, 4 b128 reads feed 2 queries ----
#pragma unroll
        for (int k = 0; k < SCHUNK / 2; ++k) {
            const int sl = sl0 + k;
            const float* sr = sp + sl * SROW + sbase;
            const float4 s0 = *reinterpret_cast<const float4*>(sr +  0);
            const float4 s1 = *reinterpret_cast<const float4*>(sr +  4);
            const float4 s2 = *reinterpret_cast<const float4*>(sr +  8);
            const float4 s3 = *reinterpret_cast<const float4*>(sr + 12);

            float scA = 0.0f, sqA = 0.0f, scB = 0.0f, sqB = 0.0f;
            ACC4(a0, w0, s0, scA, sqA) ACC4(a1, w1, s1, scA, sqA)
            ACC4(a2, w2, s2, scA, sqA) ACC4(a3, w3, s3, scA, sqA)
            ACC4(b0, w0, s0, scB, sqB) ACC4(b1, w1, s1, scB, sqB)
            ACC4(b2, w2, s2, scB, sqB) ACC4(b3, w3, s3, scB, sqB)

            const int pb = sl * SLSTR + dseg * PQS + qpair;
            praw_sc[pb]     = scA;
            praw_sq[pb]     = sqA;
            praw_sc[pb + 8] = scB;
            praw_sq[pb + 8] = sqB;
        }
        __syncthreads();

        // ---- per-pass reduce over 32 dsegs: fixed order, deterministic ----
        if (tid < SCHUNK * QT) {              // 96 threads
            const int sl = tid >> 4, qq = tid & 15;
            const int b = sl * SLSTR + qq;
            float sc = 0.0f, sq = 0.0f;
#pragma unroll
            for (int d = 0; d < 32; ++d) {
                sc += praw_sc[b + d * PQS];
                sq += praw_sq[b + d * PQS];
            }
            part[qq * PSTR + pass * SCHUNK + sl] = make_float2(sc, sq);
        }
    }
#undef ACC4
    __syncthreads();   // all part[] writes visible

    // ---- epilogue: 16 half-wave groups; group g = query g ----
    const int grp  = tid >> 5;                // 0..15
    const int s32  = tid & 31;
    const bool valid = (s32 < SN);
    const int  si  = valid ? s32 : 0;

    float dy = 0.0f;
    if (valid)
        dy = support_y[s32] - 1.0f / (1.0f + expf(-support_pr[s32]));

    const int ns = num_samples[0];
    const float ascale = fabsf(adj_scale[ns - 1]);
    const float abias  = adj_bias[ns - 1];

    const int qg = blockIdx.x * QT + grp;
    const float2 pr = part[grp * PSTR + si];

    float scv = valid ? pr.x : -1e30f;
    float ssv = valid ? pr.y : 0.0f;

    float m = scv;
#pragma unroll
    for (int off = 16; off >= 1; off >>= 1)
        m = fmaxf(m, __shfl_xor(m, off));

    float e   = valid ? expf(scv - m) : 0.0f;
    float den = e;
    float num = dy * e;
    float l2  = valid ? sqrtf(ssv) : 0.0f;
#pragma unroll
    for (int off = 16; off >= 1; off >>= 1) {
        den += __shfl_xor(den, off);
        num += __shfl_xor(num, off);
        l2  += __shfl_xor(l2,  off);
    }

    if (s32 == 0) {
        out[qg]      = num / den * ascale + abias + query_pr[qg];
        out[QN + qg] = l2 * (1.0f / (float)SN);
    }
}

extern "C" void kernel_launch(void* const* d_in, const int* in_sizes, int n_in,
                              void* d_out, int out_size, void* d_ws, size_t ws_size,
                              hipStream_t stream)
{
    const float* query      = (const float*)d_in[0];
    const float* support    = (const float*)d_in[1];
    const float* support_y  = (const float*)d_in[2];
    const float* support_pr = (const float*)d_in[3];
    const float* query_pr   = (const float*)d_in[4];
    const float* fc1_w      = (const float*)d_in[5];
    // d_in[6] = fc1_b: cancels in softmax, unused
    const float* adj_scale  = (const float*)d_in[7];
    const float* adj_bias   = (const float*)d_in[8];
    const int*   num_s      = (const int*)d_in[9];
    float* out = (float*)d_out;

    dim3 grid(QN / QT);      // 512 blocks x 8 waves = 4096 waves = 4/SIMD
    hipLaunchKernelGGL(resus_one, grid, dim3(BLK), 0, stream,
                       query, support, support_y, support_pr, query_pr,
                       fc1_w, adj_scale, adj_bias, num_s, out);
}